// Round 6
// baseline (137.029 us; speedup 1.0000x reference)
//
#include <hip/hip_runtime.h>
#include <math.h>

// BRF elementwise dynamics, fp32. out layout: [z | u_ | v_new | q_new].
// Grid-stride, pair-adjacent unroll: each thread handles float4 indices
// {2p, 2p+1}, so a wave's accesses form a contiguous 2KB run per stream.
// Column pair is invariant across grid-stride iterations (stride % D4 == 0),
// so per-column coefficients are computed once per thread, IEEE-exact.

#define DTF ((float)(1.0 / 24000.0))
#define QDECAY 0.9f

typedef float f32x4 __attribute__((ext_vector_type(4)));

__device__ __forceinline__ void brf_elem(float x, float u, float v, float q,
                                         float om, float pw, float th,
                                         float& z, float& u_, float& vn, float& qn) {
#pragma clang fp contract(off)
    float b  = pw - q;                                   // (p_omega-|bs|) - q
    float t1 = (b * u) * DTF;
    float t2 = (om * v) * DTF;
    float t3 = x * DTF;
    u_ = ((u + t1) - t2) + t3;
    float t4 = (om * u) * DTF;
    float t5 = (b * v) * DTF;
    vn = (v + t4) + t5;
    float s = (fabsf(u_) - th) - q;
    z  = (s > 0.0f) ? 1.0f : 0.0f;
    qn = q * QDECAY + z;
}

__device__ __forceinline__ void coef_col(float om_in, float bs_in, float th_in,
                                         float& om, float& pw, float& th) {
#pragma clang fp contract(off)
    om = fabsf(om_in);
    float t  = DTF * om;
    float tt = t * t;                 // jnp.square
    float s  = sqrtf(1.0f - tt);      // IEEE sqrt
    float p  = (-1.0f + s) / DTF;     // IEEE div
    pw = p - fabsf(bs_in);
    th = fabsf(th_in);
}

__global__ __launch_bounds__(256) void brf_fused_kernel(
        const f32x4* __restrict__ x, const f32x4* __restrict__ u,
        const f32x4* __restrict__ v, const f32x4* __restrict__ q,
        const float* __restrict__ omegas, const float* __restrict__ bs,
        const float* __restrict__ threshold, float* __restrict__ out,
        int N4, int D4) {
#pragma clang fp contract(off)
    f32x4* out_z = (f32x4*)out;
    f32x4* out_u = out_z + (size_t)N4;
    f32x4* out_v = out_z + 2 * (size_t)N4;
    f32x4* out_q = out_z + 3 * (size_t)N4;

    const int tid    = blockIdx.x * blockDim.x + threadIdx.x;
    const int stride = gridDim.x * blockDim.x;  // launcher guarantees stride % D4 == 0
    const int P      = N4 >> 1;                 // number of float4 pairs
    const int c0     = (2 * tid) % D4;          // even; c1 = c0+1 < D4 (D4 even)

    // --- per-column coefficients for the thread's two adjacent columns ---
    f32x4 o0 = ((const f32x4*)omegas)[c0],     o1 = ((const f32x4*)omegas)[c0 + 1];
    f32x4 s0 = ((const f32x4*)bs)[c0],         s1 = ((const f32x4*)bs)[c0 + 1];
    f32x4 h0 = ((const f32x4*)threshold)[c0],  h1 = ((const f32x4*)threshold)[c0 + 1];
    float ocA[4], pwA[4], tcA[4], ocB[4], pwB[4], tcB[4];
#pragma unroll
    for (int k = 0; k < 4; ++k) {
        coef_col(o0[k], s0[k], h0[k], ocA[k], pwA[k], tcA[k]);
        coef_col(o1[k], s1[k], h1[k], ocB[k], pwB[k], tcB[k]);
    }

    for (int p = tid; p < P; p += stride) {
        int i0 = 2 * p, i1 = i0 + 1;
        f32x4 xa = __builtin_nontemporal_load(&x[i0]);
        f32x4 xb = __builtin_nontemporal_load(&x[i1]);
        f32x4 ua = __builtin_nontemporal_load(&u[i0]);
        f32x4 ub = __builtin_nontemporal_load(&u[i1]);
        f32x4 va = __builtin_nontemporal_load(&v[i0]);
        f32x4 vb = __builtin_nontemporal_load(&v[i1]);
        f32x4 qa = __builtin_nontemporal_load(&q[i0]);
        f32x4 qb = __builtin_nontemporal_load(&q[i1]);

        f32x4 rza, rua, rva, rqa, rzb, rub, rvb, rqb;
#pragma unroll
        for (int k = 0; k < 4; ++k) {
            float z, u_, vn, qn;
            brf_elem(xa[k], ua[k], va[k], qa[k], ocA[k], pwA[k], tcA[k], z, u_, vn, qn);
            rza[k] = z; rua[k] = u_; rva[k] = vn; rqa[k] = qn;
        }
#pragma unroll
        for (int k = 0; k < 4; ++k) {
            float z, u_, vn, qn;
            brf_elem(xb[k], ub[k], vb[k], qb[k], ocB[k], pwB[k], tcB[k], z, u_, vn, qn);
            rzb[k] = z; rub[k] = u_; rvb[k] = vn; rqb[k] = qn;
        }

        __builtin_nontemporal_store(rza, &out_z[i0]);
        __builtin_nontemporal_store(rzb, &out_z[i1]);
        __builtin_nontemporal_store(rua, &out_u[i0]);
        __builtin_nontemporal_store(rub, &out_u[i1]);
        __builtin_nontemporal_store(rva, &out_v[i0]);
        __builtin_nontemporal_store(rvb, &out_v[i1]);
        __builtin_nontemporal_store(rqa, &out_q[i0]);
        __builtin_nontemporal_store(rqb, &out_q[i1]);
    }

    // odd leftover float4 (N4 odd) — handled by one thread
    if ((N4 & 1) && tid == 0) {
        int i = N4 - 1;
        int c = i % D4;
        f32x4 ov = ((const f32x4*)omegas)[c];
        f32x4 sv = ((const f32x4*)bs)[c];
        f32x4 hv = ((const f32x4*)threshold)[c];
        f32x4 xv = x[i], uv = u[i], vv = v[i], qv = q[i];
        f32x4 rz, ru, rv, rq;
#pragma unroll
        for (int k = 0; k < 4; ++k) {
            float oc, pw, tc, z, u_, vn, qn;
            coef_col(ov[k], sv[k], hv[k], oc, pw, tc);
            brf_elem(xv[k], uv[k], vv[k], qv[k], oc, pw, tc, z, u_, vn, qn);
            rz[k] = z; ru[k] = u_; rv[k] = vn; rq[k] = qn;
        }
        out_z[i] = rz; out_u[i] = ru; out_v[i] = rv; out_q[i] = rq;
    }
}

extern "C" void kernel_launch(void* const* d_in, const int* in_sizes, int n_in,
                              void* d_out, int out_size, void* d_ws, size_t ws_size,
                              hipStream_t stream) {
    const float* x   = (const float*)d_in[0];
    const float* u   = (const float*)d_in[1];
    const float* v   = (const float*)d_in[2];
    const float* q   = (const float*)d_in[3];
    const float* om  = (const float*)d_in[4];
    const float* bs  = (const float*)d_in[5];
    const float* th  = (const float*)d_in[6];
    float* out = (float*)d_out;

    int N  = in_sizes[0];   // B*D
    int D  = in_sizes[4];
    int N4 = N / 4;
    int D4 = D / 4;

    int blocks = ((N4 / 2) + 255) / 256;
    if (blocks > 2048) blocks = 2048;
    // Round blocks so stride is a multiple of D4 -> column pair invariant
    // across grid-stride iterations.
    {
        int g = 256, b = D4;            // gcd(256, D4)
        while (b) { int t = g % b; g = b; b = t; }
        int m = D4 / g;                 // blocks must be a multiple of m
        blocks = ((blocks + m - 1) / m) * m;
    }

    brf_fused_kernel<<<blocks, 256, 0, stream>>>(
        (const f32x4*)x, (const f32x4*)u, (const f32x4*)v, (const f32x4*)q,
        om, bs, th, out, N4, D4);
}

// Round 7
// 98.498 us; speedup vs baseline: 1.3912x; 1.3912x over previous
//
#include <hip/hip_runtime.h>
#include <math.h>

// BRF elementwise dynamics, fp32. out layout: [z | u_ | v_new | q_new].
// Block-tiled x2 unroll: per grid-stride iteration each block covers a
// contiguous 512-float4 (8KB) window per stream; thread t handles window
// offsets t and t+256. Every load/store is a fully lane-coalesced 1KB
// wave access, and the block's accesses form one contiguous 8KB burst.
// Column indices are invariant across iterations (stride % D4 == 0), so
// per-column coefficients are computed once per thread, IEEE-exact.

#define DTF ((float)(1.0 / 24000.0))
#define QDECAY 0.9f

typedef float f32x4 __attribute__((ext_vector_type(4)));

__device__ __forceinline__ void brf_elem(float x, float u, float v, float q,
                                         float om, float pw, float th,
                                         float& z, float& u_, float& vn, float& qn) {
#pragma clang fp contract(off)
    float b  = pw - q;                                   // (p_omega-|bs|) - q
    float t1 = (b * u) * DTF;
    float t2 = (om * v) * DTF;
    float t3 = x * DTF;
    u_ = ((u + t1) - t2) + t3;
    float t4 = (om * u) * DTF;
    float t5 = (b * v) * DTF;
    vn = (v + t4) + t5;
    float s = (fabsf(u_) - th) - q;
    z  = (s > 0.0f) ? 1.0f : 0.0f;
    qn = q * QDECAY + z;
}

__device__ __forceinline__ void coef_col(float om_in, float bs_in, float th_in,
                                         float& om, float& pw, float& th) {
#pragma clang fp contract(off)
    om = fabsf(om_in);
    float t  = DTF * om;
    float tt = t * t;                 // jnp.square
    float s  = sqrtf(1.0f - tt);      // IEEE sqrt
    float p  = (-1.0f + s) / DTF;     // IEEE div
    pw = p - fabsf(bs_in);
    th = fabsf(th_in);
}

__global__ __launch_bounds__(256) void brf_fused_kernel(
        const f32x4* __restrict__ x, const f32x4* __restrict__ u,
        const f32x4* __restrict__ v, const f32x4* __restrict__ q,
        const float* __restrict__ omegas, const float* __restrict__ bs,
        const float* __restrict__ threshold, float* __restrict__ out,
        int N4, int D4, int nFull) {
#pragma clang fp contract(off)
    f32x4* out_z = (f32x4*)out;
    f32x4* out_u = out_z + (size_t)N4;
    f32x4* out_v = out_z + 2 * (size_t)N4;
    f32x4* out_q = out_z + 3 * (size_t)N4;

    const int stride = gridDim.x * 512;          // float4s per full iteration
    const int base0  = blockIdx.x * 512 + threadIdx.x;       // slice A
    const int base1  = base0 + 256;                          // slice B

    // --- per-column coefficients for both slices (invariant: stride % D4 == 0) ---
    const int cA = base0 % D4;
    const int cB = base1 % D4;
    f32x4 oA = ((const f32x4*)omegas)[cA],    oB = ((const f32x4*)omegas)[cB];
    f32x4 sA = ((const f32x4*)bs)[cA],        sB = ((const f32x4*)bs)[cB];
    f32x4 hA = ((const f32x4*)threshold)[cA], hB = ((const f32x4*)threshold)[cB];
    float ocA[4], pwA[4], tcA[4], ocB[4], pwB[4], tcB[4];
#pragma unroll
    for (int k = 0; k < 4; ++k) {
        coef_col(oA[k], sA[k], hA[k], ocA[k], pwA[k], tcA[k]);
        coef_col(oB[k], sB[k], hB[k], ocB[k], pwB[k], tcB[k]);
    }

    for (int i0 = base0; i0 < nFull; i0 += stride) {
        int i1 = i0 + 256;
        f32x4 xa = __builtin_nontemporal_load(&x[i0]);
        f32x4 xb = __builtin_nontemporal_load(&x[i1]);
        f32x4 ua = __builtin_nontemporal_load(&u[i0]);
        f32x4 ub = __builtin_nontemporal_load(&u[i1]);
        f32x4 va = __builtin_nontemporal_load(&v[i0]);
        f32x4 vb = __builtin_nontemporal_load(&v[i1]);
        f32x4 qa = __builtin_nontemporal_load(&q[i0]);
        f32x4 qb = __builtin_nontemporal_load(&q[i1]);

        f32x4 rza, rua, rva, rqa, rzb, rub, rvb, rqb;
#pragma unroll
        for (int k = 0; k < 4; ++k) {
            float z, u_, vn, qn;
            brf_elem(xa[k], ua[k], va[k], qa[k], ocA[k], pwA[k], tcA[k], z, u_, vn, qn);
            rza[k] = z; rua[k] = u_; rva[k] = vn; rqa[k] = qn;
        }
#pragma unroll
        for (int k = 0; k < 4; ++k) {
            float z, u_, vn, qn;
            brf_elem(xb[k], ub[k], vb[k], qb[k], ocB[k], pwB[k], tcB[k], z, u_, vn, qn);
            rzb[k] = z; rub[k] = u_; rvb[k] = vn; rqb[k] = qn;
        }

        __builtin_nontemporal_store(rza, &out_z[i0]);
        __builtin_nontemporal_store(rzb, &out_z[i1]);
        __builtin_nontemporal_store(rua, &out_u[i0]);
        __builtin_nontemporal_store(rub, &out_u[i1]);
        __builtin_nontemporal_store(rva, &out_v[i0]);
        __builtin_nontemporal_store(rvb, &out_v[i1]);
        __builtin_nontemporal_store(rqa, &out_q[i0]);
        __builtin_nontemporal_store(rqb, &out_q[i1]);
    }

    // tail: [nFull, N4), per-element coef compute (IEEE-exact), grid-stride
    for (int i = nFull + blockIdx.x * 256 + threadIdx.x; i < N4; i += gridDim.x * 256) {
        int c = i % D4;
        f32x4 ov = ((const f32x4*)omegas)[c];
        f32x4 sv = ((const f32x4*)bs)[c];
        f32x4 hv = ((const f32x4*)threshold)[c];
        f32x4 xv = x[i], uv = u[i], vv = v[i], qv = q[i];
        f32x4 rz, ru, rv, rq;
#pragma unroll
        for (int k = 0; k < 4; ++k) {
            float oc, pw, tc, z, u_, vn, qn;
            coef_col(ov[k], sv[k], hv[k], oc, pw, tc);
            brf_elem(xv[k], uv[k], vv[k], qv[k], oc, pw, tc, z, u_, vn, qn);
            rz[k] = z; ru[k] = u_; rv[k] = vn; rq[k] = qn;
        }
        out_z[i] = rz; out_u[i] = ru; out_v[i] = rv; out_q[i] = rq;
    }
}

extern "C" void kernel_launch(void* const* d_in, const int* in_sizes, int n_in,
                              void* d_out, int out_size, void* d_ws, size_t ws_size,
                              hipStream_t stream) {
    const float* x   = (const float*)d_in[0];
    const float* u   = (const float*)d_in[1];
    const float* v   = (const float*)d_in[2];
    const float* q   = (const float*)d_in[3];
    const float* om  = (const float*)d_in[4];
    const float* bs  = (const float*)d_in[5];
    const float* th  = (const float*)d_in[6];
    float* out = (float*)d_out;

    int N  = in_sizes[0];   // B*D
    int D  = in_sizes[4];
    int N4 = N / 4;
    int D4 = D / 4;

    int blocks = (N4 + 511) / 512;
    if (blocks > 2048) blocks = 2048;
    // Round blocks so stride (= blocks*512 float4s) is a multiple of D4:
    // column indices invariant across grid-stride iterations.
    {
        int g = 512, b = D4;            // gcd(512, D4)
        while (b) { int t = g % b; g = b; b = t; }
        int m = D4 / g;                 // blocks must be a multiple of m
        blocks = ((blocks + m - 1) / m) * m;
    }

    int per_iter = blocks * 512;
    int nFull = (N4 / per_iter) * per_iter;   // main loop covers [0, nFull)

    brf_fused_kernel<<<blocks, 256, 0, stream>>>(
        (const f32x4*)x, (const f32x4*)u, (const f32x4*)v, (const f32x4*)q,
        om, bs, th, out, N4, D4, nFull);
}